// Round 2
// baseline (2123.893 us; speedup 1.0000x reference)
//
#include <hip/hip_runtime.h>
#include <stdint.h>

// LSTM_Trend: B=256, T=512, F=64, H=512, P=24.
// Persistent kernel: 256 WGs x 256 threads (1/CU) = 16 pair-groups x 16
// hidden-groups. Weights register-resident as MFMA B-fragments (144 VGPRs,
// shared by both chains). DUAL-CHAIN LATENCY HIDING: each WG runs TWO
// independent 8-row batch chains (rows [pg*8,+8) and [128+pg*8,+8)),
// phase-shifted by half a step. While chain A's h-exchange is in flight,
// the WG computes chain B, and vice versa -- the L3 store-visibility +
// detect latency (which R0/R1 showed dominates the 2.8us step and is
// insensitive to round-trip count) hides under the other chain's compute.
// Exchange: self-validating tagged dwords (bf16(h)<<16 | t+1) via sc0sc1;
// polls are issued ~one compute-phase after the matching stores, so the
// first round nearly always succeeds (kills R1's retry-flood pathology).
// Both chains share one 24-row LDS A-tile (rows 16..23 zero padding for
// chain B's MFMA m-range; kq<2 masks garbage output rows); h_T for both
// chains ends LDS-resident so the FC head needs no coherent loads.

namespace {
constexpr int T_STEPS = 512;
constexpr int FEA  = 64;
constexpr int HID  = 512;
constexpr int KTOT = HID + FEA;   // 576
constexpr int KPAD = KTOT + 8;    // 584 bf16 = 1168 B rows (16B skew)
constexpr int NKI  = KTOT / 32;   // 18 K-iterations
constexpr int GSTR = 132;         // gates LDS row stride (floats)
constexpr int RPC  = 8;           // batch rows per chain
constexpr size_t HBUF_DW = 256ull * 512;   // tagged dwords per buffer

typedef __bf16   bf16x8 __attribute__((ext_vector_type(8)));
typedef uint16_t u16x8  __attribute__((ext_vector_type(8)));
typedef float    f32x4  __attribute__((ext_vector_type(4)));
typedef uint32_t u32x4  __attribute__((ext_vector_type(4)));

union V8 { u16x8 u; bf16x8 b; u32x4 q; };

__device__ __forceinline__ float bf2f(uint16_t u) {
  union { uint32_t i; float f; } v; v.i = (uint32_t)u << 16; return v.f;
}
__device__ __forceinline__ uint16_t f2bf(float f) {
  union { float f; uint32_t i; } v; v.f = f;
  uint32_t x = v.i;
  return (uint16_t)((x + 0x7FFFu + ((x >> 16) & 1u)) >> 16);  // RNE
}
__device__ __forceinline__ float sigmoid_f(float x) {
  return 1.0f / (1.0f + __expf(-x));
}
__device__ __forceinline__ float tanh_f(float x) {
  float e = __expf(-2.0f * fabsf(x));
  float t = (1.0f - e) / (1.0f + e);
  return copysignf(t, x);
}
__device__ __forceinline__ bf16x8 load8(const void* base, size_t elem_off,
                                        bool fp32m) {
  V8 r;
  if (fp32m) {
    const float* p = (const float*)base + elem_off;
#pragma unroll
    for (int i = 0; i < 8; ++i) r.u[i] = f2bf(p[i]);
  } else {
    r.q = *(const u32x4*)((const uint16_t*)base + elem_off);
  }
  return r.b;
}
__device__ __forceinline__ float loadf(const void* base, int idx, bool fp32m) {
  return fp32m ? ((const float*)base)[idx] : bf2f(((const uint16_t*)base)[idx]);
}

// ---- explicit L3-coherent (L1/L2-bypass) memory ops -----------------------
__device__ __forceinline__ u32x4 ld128_sc01(const uint32_t* p) {
  u32x4 v;
  asm volatile("global_load_dwordx4 %0, %1, off sc0 sc1"
               : "=v"(v) : "v"(p) : "memory");
  return v;
}
__device__ __forceinline__ void st32_sc01(uint32_t* p, uint32_t v) {
  asm volatile("global_store_dword %0, %1, off sc0 sc1"
               :: "v"(p), "v"(v) : "memory");
}
__device__ __forceinline__ void waitcnt_vm0() {
  asm volatile("s_waitcnt vmcnt(0)" ::: "memory");
}
} // namespace

__global__ __launch_bounds__(256, 1) void lstm_persistent(
    const void* __restrict__ x,      // [256][512][64]
    const void* __restrict__ W_ih,   // [2048][64]
    const void* __restrict__ W_hh,   // [2048][512]
    const void* __restrict__ b_ih,   // [2048]
    const void* __restrict__ b_hh,   // [2048]
    const void* __restrict__ W_fc,   // [1536][512]
    const void* __restrict__ b_fc,   // [1536]
    void* __restrict__ out,          // [256][1536]
    uint32_t* __restrict__ hbuf)     // [2][256][512] tagged dwords (workspace)
{
  __shared__ __align__(16) uint16_t Als[24 * KPAD];  // rows 0..7 A, 8..15 B,
                                                     // 16..23 zero m-padding
  __shared__ float Gls[RPC * GSTR];  // gate pre-activations (one chain)
  __shared__ int   sflag;

  const int tid = threadIdx.x;
  const int wv  = tid >> 6;              // wave 0..3
  const int ln  = tid & 63;
  const int nl  = ln & 15;               // MFMA m/n lane index
  const int kq  = ln >> 4;               // MFMA k-quad
  const int pg  = blockIdx.x & 15;       // pair group (peers share XCD mod 8)
  const int wgi = blockIdx.x >> 4;       // hidden group 0..15
  const int growA = pg * RPC;            // chain A batch rows [growA, +8)
  const int growB = 128 + pg * RPC;      // chain B batch rows

  // ---- dtype sniff (block-uniform): fp32 read as bf16 -> huge exponents
  if (tid == 0) sflag = 0;
  __syncthreads();
  {
    float a = fabsf(bf2f(((const uint16_t*)b_ih)[tid]));
    if (a > 1.0f) atomicOr(&sflag, 1);
  }
  __syncthreads();
  const bool fp32m = (sflag != 0);

  // wave owns cols [wv*32, wv*32+32) as two 16-col subtiles sharing one A-frag
  bf16x8 breg[2][NKI];
  float  bias[2];
#pragma unroll
  for (int s = 0; s < 2; ++s) {
    int col  = wv * 32 + s * 16 + nl;    // 0..127
    int gate = col & 3;
    int unit = col >> 2;                 // 0..31
    int gcol = gate * HID + wgi * 32 + unit;
#pragma unroll
    for (int kk = 0; kk < NKI; ++kk) {
      int k0 = kk * 32 + kq * 8;
      if (k0 < HID)
        breg[s][kk] = load8(W_hh, (size_t)gcol * HID + k0, fp32m);
      else
        breg[s][kk] = load8(W_ih, (size_t)gcol * FEA + (k0 - HID), fp32m);
    }
    bias[s] = loadf(b_ih, gcol, fp32m) + loadf(b_hh, gcol, fp32m);
  }

  // per-chain thread roles: row prow (0..7), unit-col pcol (0..31)
  const int prow = tid >> 5;
  const int pcol = tid & 31;
  // poll chunks: thread covers units [pcol*16, +16) = 4 x dwordx4;
  // own WG's 32-unit span (written to LDS directly) is skipped entirely.
  const uint32_t pend0 = ((pcol >> 1) == wgi) ? 0u : 0xFu;

  // ---- prologue: zero Als (h(0)=0 + m-padding rows), stage x_0 both chains
  {
    u32x4 z = {0, 0, 0, 0};
    for (int i = tid; i < 24 * KPAD / 8; i += 256) ((u32x4*)Als)[i] = z;
  }
  __syncthreads();
#pragma unroll
  for (int ch = 0; ch < 2; ++ch) {
    int grow = (ch ? growB : growA) + prow;
    size_t off = (size_t)grow * (T_STEPS * FEA) + pcol * 2;
    uint32_t w;
    if (fp32m) {
      const float2 xv = *(const float2*)((const float*)x + off);
      w = (uint32_t)f2bf(xv.x) | ((uint32_t)f2bf(xv.y) << 16);
    } else {
      w = *(const uint32_t*)((const uint16_t*)x + off);
    }
    *(uint32_t*)&Als[(ch * RPC + prow) * KPAD + HID + pcol * 2] = w;
  }

  float cA = 0.0f, cB = 0.0f;

  auto mfma_phase = [&](int rowbase) {
    f32x4 a0, a1;
    a0[0] = bias[0]; a0[1] = bias[0]; a0[2] = bias[0]; a0[3] = bias[0];
    a1[0] = bias[1]; a1[1] = bias[1]; a1[2] = bias[1]; a1[3] = bias[1];
#pragma unroll
    for (int kk = 0; kk < NKI; ++kk) {
      bf16x8 a = *(const bf16x8*)&Als[(rowbase + nl) * KPAD + kk * 32 + kq * 8];
      a0 = __builtin_amdgcn_mfma_f32_16x16x32_bf16(a, breg[0][kk], a0, 0, 0, 0);
      a1 = __builtin_amdgcn_mfma_f32_16x16x32_bf16(a, breg[1][kk], a1, 0, 0, 0);
    }
    if (kq < 2) {                        // rows 8..15 are m-padding garbage
#pragma unroll
      for (int r = 0; r < 4; ++r) {
        Gls[(kq * 4 + r) * GSTR + wv * 32 + nl]      = a0[r];
        Gls[(kq * 4 + r) * GSTR + wv * 32 + 16 + nl] = a1[r];
      }
    }
  };

  auto poll_phase = [&](int ch, int growbase, uint32_t tag) {
    uint32_t pend = pend0;
    if (!pend) return;
    const uint32_t* pr = hbuf + (size_t)(tag & 1) * HBUF_DW
                       + (size_t)(growbase + prow) * 512 + pcol * 16;
    uint16_t* dst = &Als[(ch * RPC + prow) * KPAD + pcol * 16];
    u32x4 v[4];
    for (;;) {
#pragma unroll
      for (int c = 0; c < 4; ++c)
        if (pend & (1u << c)) v[c] = ld128_sc01(pr + 4 * c);
      waitcnt_vm0();
#pragma unroll
      for (int c = 0; c < 4; ++c)
        if (pend & (1u << c)) {
          uint32_t m = ((v[c][0] ^ tag) | (v[c][1] ^ tag) |
                        (v[c][2] ^ tag) | (v[c][3] ^ tag)) & 0xFFFFu;
          if (m == 0) {
            uint2 w;
            w.x = (v[c][0] >> 16) | (v[c][1] & 0xFFFF0000u);
            w.y = (v[c][2] >> 16) | (v[c][3] & 0xFFFF0000u);
            *(uint2*)&dst[c * 4] = w;
            pend &= ~(1u << c);
          }
        }
      if (!pend) break;
      __builtin_amdgcn_s_sleep(1);
    }
  };

  for (int t = 0; t < T_STEPS; ++t) {
    const uint32_t tg = (uint32_t)(t + 1);
    const bool havex = (t + 1 < T_STEPS);

    __syncthreads();                     // S0: Als_A ready, Gls free
    // prefetch x_A(t+1) (latency hides under MFMA A)
    uint32_t xwA = 0; float2 xfA;
    if (havex) {
      size_t off = (size_t)(growA + prow) * (T_STEPS * FEA)
                 + (size_t)(t + 1) * FEA + pcol * 2;
      if (fp32m) xfA = *(const float2*)((const float*)x + off);
      else       xwA = *(const uint32_t*)((const uint16_t*)x + off);
    }
    mfma_phase(0);
    __syncthreads();                     // S1: Gls ready, Als_A MFMA-reads done
    {  // act A: c,h update; own slice -> LDS; tagged store; x(t+1) -> LDS
      const f32x4 g = *(const f32x4*)&Gls[prow * GSTR + pcol * 4];
      cA = sigmoid_f(g[1]) * cA + sigmoid_f(g[0]) * tanh_f(g[2]);
      float h = sigmoid_f(g[3]) * tanh_f(cA);
      uint32_t hb = f2bf(h);
      Als[prow * KPAD + wgi * 32 + pcol] = (uint16_t)hb;
      st32_sc01(hbuf + (size_t)(tg & 1) * HBUF_DW
                     + (size_t)(growA + prow) * 512 + wgi * 32 + pcol,
                (hb << 16) | tg);
      if (havex) {
        uint32_t w = xwA;
        if (fp32m) w = (uint32_t)f2bf(xfA.x) | ((uint32_t)f2bf(xfA.y) << 16);
        *(uint32_t*)&Als[prow * KPAD + HID + pcol * 2] = w;
      }
    }
    if (t > 0) poll_phase(1, growB, (uint32_t)t);  // h_B(t): stored ~1 phase ago

    __syncthreads();                     // S2: Als_B ready, Gls free
    uint32_t xwB = 0; float2 xfB;
    if (havex) {
      size_t off = (size_t)(growB + prow) * (T_STEPS * FEA)
                 + (size_t)(t + 1) * FEA + pcol * 2;
      if (fp32m) xfB = *(const float2*)((const float*)x + off);
      else       xwB = *(const uint32_t*)((const uint16_t*)x + off);
    }
    mfma_phase(RPC);
    __syncthreads();                     // S3: Gls ready
    {  // act B
      const f32x4 g = *(const f32x4*)&Gls[prow * GSTR + pcol * 4];
      cB = sigmoid_f(g[1]) * cB + sigmoid_f(g[0]) * tanh_f(g[2]);
      float h = sigmoid_f(g[3]) * tanh_f(cB);
      uint32_t hb = f2bf(h);
      Als[(RPC + prow) * KPAD + wgi * 32 + pcol] = (uint16_t)hb;
      st32_sc01(hbuf + (size_t)(tg & 1) * HBUF_DW
                     + (size_t)(growB + prow) * 512 + wgi * 32 + pcol,
                (hb << 16) | tg);
      if (havex) {
        uint32_t w = xwB;
        if (fp32m) w = (uint32_t)f2bf(xfB.x) | ((uint32_t)f2bf(xfB.y) << 16);
        *(uint32_t*)&Als[(RPC + prow) * KPAD + HID + pcol * 2] = w;
      }
    }
    poll_phase(0, growA, tg);            // h_A(t+1): stored ~1 phase ago
  }
  poll_phase(1, growB, (uint32_t)T_STEPS);  // h_B(512) for FC head
  __syncthreads();                       // h_T both chains resident in Als

  // ---- FC head: out = h_T @ W_fc^T + b_fc (A-frags straight from LDS) ----
  int gwave = wgi * 4 + wv;              // 0..63 within the pair group
  for (int tile = gwave; tile < 96; tile += 64) {
    int n = tile * 16 + nl;              // out column
    float bs = loadf(b_fc, n, fp32m);
    f32x4 acc; acc[0] = bs; acc[1] = bs; acc[2] = bs; acc[3] = bs;
#pragma unroll
    for (int kk = 0; kk < 16; ++kk) {
      int k0 = kk * 32 + kq * 8;
      bf16x8 a = *(const bf16x8*)&Als[nl * KPAD + k0];
      bf16x8 b = load8(W_fc, (size_t)n * HID + k0, fp32m);
      acc = __builtin_amdgcn_mfma_f32_16x16x32_bf16(a, b, acc, 0, 0, 0);
    }
#pragma unroll
    for (int r = 0; r < 4; ++r) {
      int lr = kq * 4 + r;               // 0..15: A rows then B rows
      int grow = (lr < RPC) ? (growA + lr) : (growB + lr - RPC);
      if (fp32m) ((float*)out)[(size_t)grow * 1536 + n] = acc[r];
      else       ((uint16_t*)out)[(size_t)grow * 1536 + n] = f2bf(acc[r]);
    }
  }
}

extern "C" void kernel_launch(void* const* d_in, const int* in_sizes, int n_in,
                              void* d_out, int out_size, void* d_ws, size_t ws_size,
                              hipStream_t stream) {
  const void* x    = d_in[0];
  const void* W_ih = d_in[1];
  const void* W_hh = d_in[2];
  const void* b_ih = d_in[3];
  const void* b_hh = d_in[4];
  const void* W_fc = d_in[5];
  const void* b_fc = d_in[6];
  uint32_t* hbuf = (uint32_t*)d_ws;  // 2 x 512 KiB tagged h buffers; tags
                                     // self-validate vs 0xAA poison -> no memset

  lstm_persistent<<<dim3(256), dim3(256), 0, stream>>>(
      x, W_ih, W_hh, b_ih, b_hh, W_fc, b_fc, d_out, hbuf);
}

// Round 4
// 1042.105 us; speedup vs baseline: 2.0381x; 2.0381x over previous
//
#include <hip/hip_runtime.h>
#include <stdint.h>

// LSTM_Trend: B=256, T=512, F=64, H=512, P=24.
// Persistent kernel: 256 WGs x 256 threads (1/CU, whole chip) =
// 16 batch-groups (16 rows) x 16 hidden-groups (32 h-units = 128 gate cols).
// Weights register-resident as MFMA B-fragments (144 VGPRs). Structure is the
// proven R0 kernel (flag-protocol exchange, 4 barriers/step).
//
// R4 change: XCD-LOCAL h STORES, verified per group.
// R0-R2 showed per-step cost is dominated by the h-exchange legs, each a MALL
// round trip (~700cy) because sc0sc1 stores write through the per-XCD L2
// (WRITE_SIZE == exact h-store volume proved it). Under the observed
// blockIdx%8 -> XCD mapping, a batch-group's 16 WGs (blockIdx = wgi*16+bg)
// all share XCD bg%8 -- so their exchange can stay in that XCD's L2.
// Safety (Guideline 16: never let correctness depend on placement):
//  - per-group rendezvous: each WG ORs (1<<XCC_ID) into a group mask and
//    bumps a group counter (device-scope atomics); WGs spin on their OWN
//    group's count==16 (same co-residency the R0 flag protocol already
//    needs). xloc = popcount(mask)==1 is a MEASURED same-XCD check.
//    Replay-safe (count grows, mask idempotent) and poison-safe (0xAA mask
//    -> fallback).
//  - only STORES change scope (sc0 -> dirty in local L2). All exchange
//    LOADS stay sc0sc1 (proven L1-bypass); a system-scope load probes the
//    local L2 on its path and hits the dirty line -> L2-hit latency, no
//    stale-L1 hang risk, no new load semantics.
//  - popcount!=1 -> exact R0 fallback (sc0sc1 stores), correct under any
//    dispatch mapping, merely slow.

namespace {
constexpr int T_STEPS = 512;
constexpr int FEA  = 64;
constexpr int HID  = 512;
constexpr int KTOT = HID + FEA;   // 576
constexpr int KPAD = KTOT + 8;    // 584 bf16 = 1168 B rows (16B skew)
constexpr int NKI  = KTOT / 32;   // 18 K-iterations
constexpr int GSTR = 132;         // gates LDS row stride (floats)
constexpr int RPG  = 16;          // batch rows per group
constexpr size_t DPAR     = 256ull * 256;       // dwords per parity buffer
constexpr size_t FLAG_OFF = 2 * DPAR;           // dword offset of flag lines
constexpr size_t GRZ_OFF  = FLAG_OFF + 16 * 16; // dword offset: gmask[16],gcnt[16]

typedef __bf16   bf16x8 __attribute__((ext_vector_type(8)));
typedef uint16_t u16x8  __attribute__((ext_vector_type(8)));
typedef float    f32x4  __attribute__((ext_vector_type(4)));
typedef uint32_t u32x4  __attribute__((ext_vector_type(4)));

union V8 { u16x8 u; bf16x8 b; u32x4 q; };

__device__ __forceinline__ float bf2f(uint16_t u) {
  union { uint32_t i; float f; } v; v.i = (uint32_t)u << 16; return v.f;
}
__device__ __forceinline__ uint16_t f2bf(float f) {
  union { float f; uint32_t i; } v; v.f = f;
  uint32_t x = v.i;
  return (uint16_t)((x + 0x7FFFu + ((x >> 16) & 1u)) >> 16);  // RNE
}
__device__ __forceinline__ float sigmoid_f(float x) {
  return 1.0f / (1.0f + __expf(-x));
}
__device__ __forceinline__ float tanh_f(float x) {
  float e = __expf(-2.0f * fabsf(x));
  float t = (1.0f - e) / (1.0f + e);
  return copysignf(t, x);
}
__device__ __forceinline__ bf16x8 load8(const void* base, size_t elem_off,
                                        bool fp32m) {
  V8 r;
  if (fp32m) {
    const float* p = (const float*)base + elem_off;
#pragma unroll
    for (int i = 0; i < 8; ++i) r.u[i] = f2bf(p[i]);
  } else {
    r.q = *(const u32x4*)((const uint16_t*)base + elem_off);
  }
  return r.b;
}
__device__ __forceinline__ float loadf(const void* base, int idx, bool fp32m) {
  return fp32m ? ((const float*)base)[idx] : bf2f(((const uint16_t*)base)[idx]);
}

// ---- exchange memory ops --------------------------------------------------
// Loads: ALWAYS sc0sc1 (L1-bypass, probes local L2 on the way -> hits dirty
// lines left by sc0 stores; proven correct in R0).
__device__ __forceinline__ uint32_t ld32_sc01(const uint32_t* p) {
  uint32_t v;
  asm volatile("global_load_dword %0, %1, off sc0 sc1"
               : "=v"(v) : "v"(p) : "memory");
  return v;
}
__device__ __forceinline__ u32x4 ld128_sc01(const uint32_t* p) {
  u32x4 v;
  asm volatile("global_load_dwordx4 %0, %1, off sc0 sc1"
               : "=v"(v) : "v"(p) : "memory");
  return v;
}
// Stores: sc0 (stay dirty in the XCD's L2) on the verified fast path,
// sc0sc1 (write through to MALL) on the fallback path.
__device__ __forceinline__ void st32_x(uint32_t* p, uint32_t v, bool xl) {
  if (xl) asm volatile("global_store_dword %0, %1, off sc0"
                       :: "v"(p), "v"(v) : "memory");
  else    asm volatile("global_store_dword %0, %1, off sc0 sc1"
                       :: "v"(p), "v"(v) : "memory");
}
__device__ __forceinline__ void waitcnt_vm0() {
  asm volatile("s_waitcnt vmcnt(0)" ::: "memory");
}
} // namespace

__global__ __launch_bounds__(256, 1) void lstm_persistent(
    const void* __restrict__ x,      // [256][512][64]
    const void* __restrict__ W_ih,   // [2048][64]
    const void* __restrict__ W_hh,   // [2048][512]
    const void* __restrict__ b_ih,   // [2048]
    const void* __restrict__ b_hh,   // [2048]
    const void* __restrict__ W_fc,   // [1536][512]
    const void* __restrict__ b_fc,   // [1536]
    void* __restrict__ out,          // [256][1536]
    uint32_t* __restrict__ dbuf)     // ws: [2][256][256] h dwords+flags+rdzv
{
  __shared__ uint16_t Als[RPG * KPAD];   // A tile: [h_{t-1} | x_t], 16 rows
  __shared__ float    Gls[RPG * GSTR];   // gate pre-activations, fp32
  __shared__ int      sflag, sok;

  const int tid = threadIdx.x;
  const int wv  = tid >> 6;              // wave 0..3
  const int ln  = tid & 63;
  const int nl  = ln & 15;               // MFMA m/n lane index
  const int kq  = ln >> 4;               // MFMA k-quad
  const int bg  = blockIdx.x & 15;       // batch group (R0 grouping)
  const int wgi = blockIdx.x >> 4;       // hidden group 0..15
  const int r0  = bg * RPG;              // first batch row of this group

  // ---- per-group XCD-identity rendezvous (one-time) -----------------------
  // All 16 WGs of group bg publish their XCC_ID; xloc iff all identical.
  if (tid == 0) {
    uint32_t xcc;
    asm volatile("s_getreg_b32 %0, hwreg(HW_REG_XCC_ID)" : "=s"(xcc));
    unsigned* gmask = (unsigned*)(dbuf + GRZ_OFF) + bg;
    unsigned* gcnt  = (unsigned*)(dbuf + GRZ_OFF) + 16 + bg;
    atomicOr(gmask, 1u << (xcc & 31));
    __threadfence();
    atomicAdd(gcnt, 1u);
    while (atomicAdd(gcnt, 0u) < 16u) __builtin_amdgcn_s_sleep(1);
    __threadfence();
    unsigned m = atomicOr(gmask, 0u);
    sok = (__popc(m) == 1) ? 1 : 0;
  }

  // ---- dtype sniff (block-uniform): fp32 read as bf16 -> huge exponents
  if (tid == 1) sflag = 0;
  __syncthreads();
  {
    float a = fabsf(bf2f(((const uint16_t*)b_ih)[tid]));
    if (a > 1.0f) atomicOr(&sflag, 1);
  }
  __syncthreads();
  const bool fp32m = (sflag != 0);
  const bool xloc  = (sok != 0);

  // wave owns cols [wv*32, wv*32+32) as two 16-col subtiles sharing one A-frag.
  // col mapping: col = 4*unit + gate  (i,f,g,o of one h-unit in 4 adj cols)
  bf16x8 breg[2][NKI];
  float  bias[2];
#pragma unroll
  for (int s = 0; s < 2; ++s) {
    int col  = wv * 32 + s * 16 + nl;    // 0..127
    int gate = col & 3;
    int unit = col >> 2;                 // 0..31
    int gcol = gate * HID + wgi * 32 + unit;
#pragma unroll
    for (int kk = 0; kk < NKI; ++kk) {
      int k0 = kk * 32 + kq * 8;
      if (k0 < HID)
        breg[s][kk] = load8(W_hh, (size_t)gcol * HID + k0, fp32m);
      else
        breg[s][kk] = load8(W_ih, (size_t)gcol * FEA + (k0 - HID), fp32m);
    }
    bias[s] = loadf(b_ih, gcol, fp32m) + loadf(b_hh, gcol, fp32m);
  }

  // activation ownership: row ar (0..15), units au, au+1
  const int ar  = tid >> 4;
  const int au  = (tid & 15) * 2;
  const int hdw = (r0 + ar) * 256 + wgi * 16 + (tid & 15);  // packed h dword
  float c0 = 0.0f, c1 = 0.0f;

  // staging: thread -> row srow; h: 4 x 16B chunks interleaved at 256B
  const int srow = tid >> 4;
  const int l16  = tid & 15;
  uint16_t* Ar = &Als[srow * KPAD];

  uint32_t* flags = dbuf + FLAG_OFF + bg * 16;  // this group's 64B flag line

  // ---- prologue: h_0 = 0 in LDS, stage x_0 ----
  {
    u32x4 z = {0, 0, 0, 0};
#pragma unroll
    for (int i = 0; i < 4; ++i) *(u32x4*)&Ar[(l16 + 16 * i) * 8] = z;
    int xo = l16 * 4;
    size_t off = (size_t)(r0 + srow) * (T_STEPS * FEA) + xo;
    uint2 w;
    if (fp32m) {
      const float4 xv = *(const float4*)((const float*)x + off);
      w.x = (uint32_t)f2bf(xv.x) | ((uint32_t)f2bf(xv.y) << 16);
      w.y = (uint32_t)f2bf(xv.z) | ((uint32_t)f2bf(xv.w) << 16);
    } else {
      w = *(const uint2*)((const uint16_t*)x + off);
    }
    *(uint2*)&Ar[HID + xo] = w;
  }

  for (int t = 0; t < T_STEPS; ++t) {
    __syncthreads();                     // S1: A tile staged

    // ---- gates = A @ W^T + bias: 18 K-steps, 1 A-frag -> 2 MFMAs ----
    f32x4 acc0, acc1;
    acc0[0] = bias[0]; acc0[1] = bias[0]; acc0[2] = bias[0]; acc0[3] = bias[0];
    acc1[0] = bias[1]; acc1[1] = bias[1]; acc1[2] = bias[1]; acc1[3] = bias[1];
#pragma unroll
    for (int kk = 0; kk < NKI; ++kk) {
      bf16x8 a = *(const bf16x8*)&Als[nl * KPAD + kk * 32 + kq * 8];
      acc0 = __builtin_amdgcn_mfma_f32_16x16x32_bf16(a, breg[0][kk], acc0, 0, 0, 0);
      acc1 = __builtin_amdgcn_mfma_f32_16x16x32_bf16(a, breg[1][kk], acc1, 0, 0, 0);
    }
#pragma unroll
    for (int r = 0; r < 4; ++r) {
      Gls[(kq * 4 + r) * GSTR + wv * 32 + nl]      = acc0[r];
      Gls[(kq * 4 + r) * GSTR + wv * 32 + 16 + nl] = acc1[r];
    }
    __syncthreads();                     // S2: gates ready, Als free

    // ---- activations, cell update, packed h store (L2-dirty on fast path) --
    {
      const f32x4* gp = (const f32x4*)&Gls[ar * GSTR + au * 4];
      f32x4 ga = gp[0], gb = gp[1];
      c0 = sigmoid_f(ga[1]) * c0 + sigmoid_f(ga[0]) * tanh_f(ga[2]);
      float h0 = sigmoid_f(ga[3]) * tanh_f(c0);
      c1 = sigmoid_f(gb[1]) * c1 + sigmoid_f(gb[0]) * tanh_f(gb[2]);
      float h1 = sigmoid_f(gb[3]) * tanh_f(c1);
      uint32_t hp = (uint32_t)f2bf(h0) | ((uint32_t)f2bf(h1) << 16);
      uint32_t* hw = dbuf + (size_t)((t + 1) & 1) * DPAR;
      st32_x(hw + hdw, hp, xloc);
    }
    waitcnt_vm0();                       // this wave's h store at L2 (/MALL)
    __syncthreads();                     // S3: whole WG's h drained

    // ---- publish flag, stage x_{t+1} (overlap), poll flags ----
    if (tid == 0) st32_x(flags + wgi, (uint32_t)(t + 1), xloc);
    if (t + 1 < T_STEPS) {
      int xo = l16 * 4;
      size_t off = (size_t)(r0 + srow) * (T_STEPS * FEA)
                   + (size_t)(t + 1) * FEA + xo;
      uint2 w;
      if (fp32m) {
        const float4 xv = *(const float4*)((const float*)x + off);
        w.x = (uint32_t)f2bf(xv.x) | ((uint32_t)f2bf(xv.y) << 16);
        w.y = (uint32_t)f2bf(xv.z) | ((uint32_t)f2bf(xv.w) << 16);
      } else {
        w = *(const uint2*)((const uint16_t*)x + off);
      }
      *(uint2*)&Ar[HID + xo] = w;
    }
    if (tid < 16) {                      // lane i waits on WG i's flag
      const uint32_t* fp = flags + tid;
      uint32_t target = (uint32_t)(t + 1);
      for (;;) {
        uint32_t c = ld32_sc01(fp);
        waitcnt_vm0();
        if (c >= target) break;
      }
    }
    __syncthreads();                     // S4: barrier passed

    // ---- load h_{t+1} (sc0sc1: probes local L2, hits dirty line) ----
    if (t + 1 < T_STEPS) {
      const uint32_t* src = dbuf + (size_t)((t + 1) & 1) * DPAR
                          + (size_t)(r0 + srow) * 256;
      u32x4 v0 = ld128_sc01(src + (l16 + 0)  * 4);
      u32x4 v1 = ld128_sc01(src + (l16 + 16) * 4);
      u32x4 v2 = ld128_sc01(src + (l16 + 32) * 4);
      u32x4 v3 = ld128_sc01(src + (l16 + 48) * 4);
      waitcnt_vm0();
      *(u32x4*)&Ar[(l16 + 0)  * 8] = v0;
      *(u32x4*)&Ar[(l16 + 16) * 8] = v1;
      *(u32x4*)&Ar[(l16 + 32) * 8] = v2;
      *(u32x4*)&Ar[(l16 + 48) * 8] = v3;
    }
  }

  // ---- FC head: out = h_T @ W_fc^T + b_fc  (h_T is in buffer 0) ----
  const uint32_t* hn = dbuf;
  int gwave = wgi * 4 + wv;                // 0..63 within the batch group
  for (int tile = gwave; tile < 96; tile += 64) {
    int n = tile * 16 + nl;                // out column
    float bs = loadf(b_fc, n, fp32m);
    f32x4 acc; acc[0] = bs; acc[1] = bs; acc[2] = bs; acc[3] = bs;
#pragma unroll
    for (int kk = 0; kk < 16; ++kk) {
      int k0 = kk * 32 + kq * 8;
      V8 av;
      av.q = ld128_sc01(hn + (size_t)(r0 + nl) * 256 + (k0 >> 1));
      bf16x8 b = load8(W_fc, (size_t)n * HID + k0, fp32m);
      waitcnt_vm0();
      acc = __builtin_amdgcn_mfma_f32_16x16x32_bf16(av.b, b, acc, 0, 0, 0);
    }
#pragma unroll
    for (int r = 0; r < 4; ++r) {
      int row = r0 + kq * 4 + r;
      if (fp32m) ((float*)out)[(size_t)row * 1536 + n] = acc[r];
      else       ((uint16_t*)out)[(size_t)row * 1536 + n] = f2bf(acc[r]);
    }
  }
}

extern "C" void kernel_launch(void* const* d_in, const int* in_sizes, int n_in,
                              void* d_out, int out_size, void* d_ws, size_t ws_size,
                              hipStream_t stream) {
  const void* x    = d_in[0];
  const void* W_ih = d_in[1];
  const void* W_hh = d_in[2];
  const void* b_ih = d_in[3];
  const void* b_hh = d_in[4];
  const void* W_fc = d_in[5];
  const void* b_fc = d_in[6];
  uint32_t* dbuf = (uint32_t*)d_ws;

  // flags (16x16 dwords) + rendezvous (gmask[16], gcnt[16]) start at 0 each
  // call (ws is poisoned 0xAA; even unzeroed, poisoned mask -> safe fallback).
  hipMemsetAsync((void*)(dbuf + FLAG_OFF), 0,
                 (16 * 16 + 32) * sizeof(uint32_t), stream);

  lstm_persistent<<<dim3(256), dim3(256), 0, stream>>>(
      x, W_ih, W_hh, b_ih, b_hh, W_fc, b_fc, d_out, dbuf);
}